// Round 14
// baseline (443.358 us; speedup 1.0000x reference)
//
#include <hip/hip_runtime.h>
#include <stdint.h>

#define B 8192
#define T 512
#define K 24

__device__ __forceinline__ float max3f(float a, float b, float c) {
    return fmaxf(fmaxf(a, b), c);   // fuses to v_max3_f32
}

#define ROR8(v) __builtin_amdgcn_mov_dpp((v), 0x128, 0xF, 0xF, true)  /* row_ror:8 == xor8 in 16-lane row */
#define XG4(v)  __builtin_amdgcn_ds_swizzle((v), 0x101F)              /* xor4 (crossbar only) */
#define D2x(v)  __builtin_amdgcn_mov_dpp((v), 0x4E, 0xF, 0xF, true)   /* quad_perm [2,3,0,1] == xor2 */
#define D1x(v)  __builtin_amdgcn_mov_dpp((v), 0xB1, 0xF, 0xF, true)   /* quad_perm [1,0,3,2] == xor1 */

// One Viterbi step, 16-lane group, 2 cols/lane. Butterfly all-gather of the
// group's 32 lane-values (lanes 12..15 hold exact duplicates of rows 22/23 —
// duplicates cannot change an order-free max). Slot (4p+c) holds row
// R(l^M[p](^1 for c>=2)) + (c&1), R(x)=2*min(x,11) — a static function of
// lane, matched by the tcr permutation at init. Exact, no LDS buffer.
__device__ __forceinline__ void vstep(float& n0, float& n1,
                                      float e0, float e1,
                                      const float (&tcr)[2][32],
                                      float* gp, bool act)
{
    const int i0 = __float_as_int(n0), i1 = __float_as_int(n1);
    const int r0 = ROR8(i0), r1 = ROR8(i1);
    const int f0 = XG4(i0), f1 = XG4(i1), f2 = XG4(r0), f3 = XG4(r1);

    int pa[8], pb[8];
    pa[0] = i0;      pb[0] = i1;        // mask 0
    pa[1] = r0;      pb[1] = r1;        // mask 8
    pa[2] = f0;      pb[2] = f1;        // mask 4
    pa[3] = f2;      pb[3] = f3;        // mask 12
    pa[4] = D2x(i0); pb[4] = D2x(i1);   // mask 2
    pa[5] = D2x(r0); pb[5] = D2x(r1);   // mask 10
    pa[6] = D2x(f0); pb[6] = D2x(f1);   // mask 6
    pa[7] = D2x(f2); pb[7] = D2x(f3);   // mask 14

    float s[32];
#pragma unroll
    for (int p = 0; p < 8; ++p) {
        s[4*p+0] = __int_as_float(pa[p]);
        s[4*p+1] = __int_as_float(pb[p]);
        s[4*p+2] = __int_as_float(D1x(pa[p]));   // mask^1
        s[4*p+3] = __int_as_float(D1x(pb[p]));
    }

    float r[2];
#pragma unroll
    for (int j = 0; j < 2; ++j) {
        float q[32];
#pragma unroll
        for (int i = 0; i < 32; ++i) q[i] = s[i] + tcr[j][i];
        float v0 = max3f(q[0],  q[1],  q[2]);
        float v1 = max3f(q[3],  q[4],  q[5]);
        float v2 = max3f(q[6],  q[7],  q[8]);
        float v3 = max3f(q[9],  q[10], q[11]);
        float v4 = max3f(q[12], q[13], q[14]);
        float v5 = max3f(q[15], q[16], q[17]);
        float v6 = max3f(q[18], q[19], q[20]);
        float v7 = max3f(q[21], q[22], q[23]);
        float v8 = max3f(q[24], q[25], q[26]);
        float v9 = max3f(q[27], q[28], q[29]);
        float vA = fmaxf(q[30], q[31]);
        float w0 = max3f(v0, v1, v2);
        float w1 = max3f(v3, v4, v5);
        float w2 = max3f(v6, v7, v8);
        float w3 = fmaxf(v9, vA);
        r[j] = fmaxf(max3f(w0, w1, w2), w3);
    }
    n0 = r[0] + e0; n1 = r[1] + e1;
    if (act) { float2 st; st.x = n0; st.y = n1; *(float2*)gp = st; }
}

// ---------------------------------------------------------------------------
// Forward Viterbi, VALUE-ONLY, register-resident alpha, 16-LANE GROUPS.
// 64-thread block = one wave = 4 batches (16-lane group each; lanes 0..11 own
// cols 2l..2l+1, lanes 12..15 compute clamped duplicates of cols 22/23 and
// skip stores). 2048 blocks -> 2048 waves = 2 waves/SIMD: TLP hides the
// dep-chain/swizzle stalls that bound the 1-wave/SIMD versions, and the DPP
// exchange has no shared reads to duplicate (unlike the LDS variant).
// 4-step-deep emission prefetch ring. Alpha_t streams to d_out[b][t][:];
// backtrack recomputes the exact argmax from it.
// ---------------------------------------------------------------------------
__global__ __launch_bounds__(64) __attribute__((amdgpu_waves_per_eu(2, 2)))
void crf_forward(const float* __restrict__ inp,    // [B, T, K]
                 const float* __restrict__ trans,  // [K, K] (prev i -> cur j)
                 float* __restrict__ out)          // [B, T, K] <- alpha
{
    const int lane = threadIdx.x;          // one wave per block
    const int g    = lane >> 4;            // batch group 0..3
    const int l    = lane & 15;            // lane within group
    const bool act = (l < 12);
    const int  lx  = act ? l : 11;         // clamped lane index
    const int  c0  = 2 * lx;               // this lane's columns c0, c0+1
    const int  b   = blockIdx.x * 4 + g;   // 2048 blocks * 4 = 8192

    // tcr[j][slot]: slot 4p+c holds row R((l^MP[p])^(c>>1)) + (c&1),
    // R(x) = 2*min(x,11). Duplicate slots get the true trans rows 22/23.
    const int MP[8] = {0, 8, 4, 12, 2, 10, 6, 14};
    float tcr[2][32];
#pragma unroll
    for (int p = 0; p < 8; ++p) {
        const int ma = (l ^ MP[p]) & 15;
        const int mb = ma ^ 1;
        const int ra = 2 * (ma < 11 ? ma : 11);
        const int rb = 2 * (mb < 11 ? mb : 11);
#pragma unroll
        for (int j = 0; j < 2; ++j) {
            tcr[j][4*p+0] = trans[(ra + 0) * K + c0 + j];
            tcr[j][4*p+1] = trans[(ra + 1) * K + c0 + j];
            tcr[j][4*p+2] = trans[(rb + 0) * K + c0 + j];
            tcr[j][4*p+3] = trans[(rb + 1) * K + c0 + j];
        }
    }

    const float* ebl = inp + (size_t)b * T * K + c0;
    float*       obl = out + (size_t)b * T * K + c0;

    float n0, n1;                          // own alpha rows c0, c0+1
    {   // t = 0: alpha_0 = emissions_0
        float2 x = *(const float2*)(ebl);
        n0 = x.x; n1 = x.y;
        if (act) *(float2*)(obl) = x;
    }

    // emission ring: eA..eD hold e(t)..e(t+3)
    float2 eA = *(const float2*)(ebl + 1 * K);
    float2 eB = *(const float2*)(ebl + 2 * K);
    float2 eC = *(const float2*)(ebl + 3 * K);
    float2 eD = *(const float2*)(ebl + 4 * K);

#pragma unroll 1
    for (int ch = 0; ch < 127; ++ch) {
        const int t = 1 + 4 * ch;              // 1,5,...,505
        // preload e(t+4..t+7); only t+7 can run past the end (clamped)
        float2 nA = *(const float2*)(ebl + (size_t)(t + 4) * K);
        float2 nB = *(const float2*)(ebl + (size_t)(t + 5) * K);
        float2 nC = *(const float2*)(ebl + (size_t)(t + 6) * K);
        int t7 = t + 7; t7 = t7 > 511 ? 511 : t7;
        float2 nD = *(const float2*)(ebl + (size_t)t7 * K);

        vstep(n0, n1, eA.x, eA.y, tcr, obl + (size_t)(t    ) * K, act);
        vstep(n0, n1, eB.x, eB.y, tcr, obl + (size_t)(t + 1) * K, act);
        vstep(n0, n1, eC.x, eC.y, tcr, obl + (size_t)(t + 2) * K, act);
        vstep(n0, n1, eD.x, eD.y, tcr, obl + (size_t)(t + 3) * K, act);

        eA = nA; eB = nB; eC = nC; eD = nD;
    }
    // tail: t = 509, 510, 511 (eA..eC already hold their emissions)
    vstep(n0, n1, eA.x, eA.y, tcr, obl + (size_t)509 * K, act);
    vstep(n0, n1, eB.x, eB.y, tcr, obl + (size_t)510 * K, act);
    vstep(n0, n1, eC.x, eC.y, tcr, obl + (size_t)511 * K, act);
}

#undef ROR8
#undef XG4
#undef D2x
#undef D1x

// ---------------------------------------------------------------------------
// 32-lane-group max reduce, all lanes receive the max. 4 DPP steps (VALU
// latency) + 1 ds_swizzle xor-16. Exact (fmax of finite floats).
// ---------------------------------------------------------------------------
__device__ __forceinline__ float groupmax32(float v) {
    float t;
    t = __int_as_float(__builtin_amdgcn_mov_dpp(__float_as_int(v), 0xB1, 0xF, 0xF, true));   // quad_perm [1,0,3,2]
    v = fmaxf(v, t);
    t = __int_as_float(__builtin_amdgcn_mov_dpp(__float_as_int(v), 0x4E, 0xF, 0xF, true));   // quad_perm [2,3,0,1]
    v = fmaxf(v, t);
    t = __int_as_float(__builtin_amdgcn_mov_dpp(__float_as_int(v), 0x141, 0xF, 0xF, true));  // row_half_mirror
    v = fmaxf(v, t);
    t = __int_as_float(__builtin_amdgcn_mov_dpp(__float_as_int(v), 0x140, 0xF, 0xF, true));  // row_mirror
    v = fmaxf(v, t);
    t = __int_as_float(__builtin_amdgcn_ds_swizzle(__float_as_int(v), 0x401F));              // xor 16
    v = fmaxf(v, t);
    return v;
}

// ---------------------------------------------------------------------------
// Fused backtrack + one-hot (unchanged — measured at the HBM floor).
// 32 lanes per batch, 2 batches/wave, 4096 waves. Per step: prefetched
// alpha_t[i] (8-deep rotation) + trans[i][cur] from stride-25 LDS -> DPP
// value-max -> cur = ctz(ballot(s == M)) (exact first-index) -> one-hot.
// ---------------------------------------------------------------------------
__global__ __launch_bounds__(256) __attribute__((amdgpu_waves_per_eu(4, 4)))
void crf_backtrack(const float* __restrict__ trans,  // [K, K]
                   float* __restrict__ out)          // [B,T,K] alpha->onehot
{
    __shared__ float tl[K * 25];      // tl[i*25 + j] = trans[i][j]

    const int tid = threadIdx.x;
    for (int idx = tid; idx < K * K; idx += 256) {
        int i = idx / K, j = idx - K * i;
        tl[i * 25 + j] = trans[idx];
    }
    __syncthreads();

    const int lane = tid & 63;
    const int half = lane >> 5;            // batch within wave (0/1)
    const int i    = lane & 31;            // tag row (24..31 idle)
    const int wv   = tid >> 6;
    const int b    = blockIdx.x * 8 + wv * 2 + half;
    const int shmt = half * 32;

    const bool act = (i < K);
    const int  io  = act ? i : (K - 1);

    float* ob = out + (size_t)b * T * K;
    const float* rp  = ob + (size_t)511 * K + io;   // prefetch pointer
    float*       wpp = ob + (size_t)511 * K + io;   // write pointer

    float q[8];                            // slot = t & 7
#pragma unroll
    for (int s = 0; s < 8; ++s) { q[7 - s] = *rp; rp -= K; }   // t=511..504

    int cur;
    {   // t = 511: last_tag = first-index argmax of alpha_511
        float s = act ? q[7] : -INFINITY;
        float M = groupmax32(s);
        uint32_t m32 = (uint32_t)(__ballot(s == M) >> shmt);
        cur = (int)__builtin_ctz(m32);
        if (act) *wpp = (i == cur) ? 1.0f : 0.0f;
        wpp -= K;
        q[7] = *rp; rp -= K;               // prefetch t=503 into slot 7
    }

#define STEP_BT(S, TT) do {                                                   \
    float tv_ = tl[io * 25 + cur];                                            \
    float s_  = act ? (q[S] + tv_) : -INFINITY;                               \
    float M_  = groupmax32(s_);                                               \
    uint32_t m32_ = (uint32_t)(__ballot(s_ == M_) >> shmt);                   \
    cur = (int)__builtin_ctz(m32_);                                           \
    if (act) *wpp = (i == cur) ? 1.0f : 0.0f;                                 \
    wpp -= K;                                                                 \
    if ((TT) >= 8) { q[S] = *rp; rp -= K; }                                   \
} while (0)

#pragma unroll 1
    for (int it = 0; it < 63; ++it) {      // t = 510 .. 7
        const int t0 = 510 - 8 * it;
        STEP_BT(6, t0);     STEP_BT(5, t0 - 1);
        STEP_BT(4, t0 - 2); STEP_BT(3, t0 - 3);
        STEP_BT(2, t0 - 4); STEP_BT(1, t0 - 5);
        STEP_BT(0, t0 - 6); STEP_BT(7, t0 - 7);
    }
    // epilogue: t = 6..0 (all slots already resident)
    STEP_BT(6, 6); STEP_BT(5, 5); STEP_BT(4, 4);
    STEP_BT(3, 3); STEP_BT(2, 2); STEP_BT(1, 1); STEP_BT(0, 0);
#undef STEP_BT
}

extern "C" void kernel_launch(void* const* d_in, const int* in_sizes, int n_in,
                              void* d_out, int out_size, void* d_ws, size_t ws_size,
                              hipStream_t stream) {
    const float* inp   = (const float*)d_in[0];   // [8192, 512, 24]
    const float* trans = (const float*)d_in[1];   // [24, 24]
    float*       out   = (float*)d_out;           // [8192, 512, 24]

    crf_forward<<<B / 4, 64, 0, stream>>>(inp, trans, out);
    crf_backtrack<<<B / 8, 256, 0, stream>>>(trans, out);
}